// Round 4
// baseline (16941.008 us; speedup 1.0000x reference)
//
#include <hip/hip_runtime.h>
#include <hip/hip_bf16.h>

#define TSTEPS 256
#define BATCH  64
#define NINP   64
#define NHID   4096
#define NGATE  (4 * NHID)        // 16384
#define KDIM   (NINP + NHID)     // 4160
#define NCHUNK (KDIM / 32)       // 130 chunks of 32 k-values
#define NGRP   (NGATE / 16)      // 1024 groups of 16 gate rows
#define NBLK   256               // 1 block per CU, 16 cols each

typedef __bf16 bf16x8 __attribute__((ext_vector_type(8)));
typedef float  f32x4  __attribute__((ext_vector_type(4)));
typedef unsigned short ushort_t;

__device__ __forceinline__ ushort_t f2b(float v) {
    __hip_bfloat16 h = __float2bfloat16(v);
    return *reinterpret_cast<ushort_t*>(&h);
}
__device__ __forceinline__ float sigf(float x) { return 1.f / (1.f + expf(-x)); }

// Fragment-linear layout (r0 original):
//   W'[grp][chunk][lane][8] : grp = gt*256 + bx covers gate gt, cols bx*16..+15
//   lane = q*16 + n holds row (grp*16+n), k = chunk*32 + q*8 .. +8
//   A'[rt ][chunk][lane][8] : lane = q*16 + n holds batch row (rt*16+n)

__global__ void k_convert(const float* __restrict__ w_ih, const float* __restrict__ w_hh,
                          const float* __restrict__ b_ih, const float* __restrict__ b_hh,
                          ushort_t* __restrict__ Wp, float* __restrict__ bias) {
    const int grp = blockIdx.x;                  // 0..1023
    for (int i = threadIdx.x; i < 16 * KDIM; i += 256) {
        int r = i / KDIM;                        // row within group 0..15
        int k = i - r * KDIM;
        int g = grp * 16 + r;                    // gate row 0..16383
        float v = (k < NINP) ? w_ih[(size_t)g * NINP + k]
                             : w_hh[(size_t)g * NHID + (k - NINP)];
        int c = k >> 5, q = (k >> 3) & 3, e = k & 7;
        Wp[((size_t)grp * NCHUNK + c) * 512 + (q * 16 + r) * 8 + e] = f2b(v);
    }
    if (threadIdx.x < 16) {
        int g = grp * 16 + threadIdx.x;
        bias[g] = b_ih[g] + b_hh[g];
    }
}

// ---- init A0' = [emb(tokens[0]) | 0] (swizzled), c = 0 ----
__global__ void k_init(const int* __restrict__ tokens, const float* __restrict__ emb,
                       ushort_t* __restrict__ A0, float* __restrict__ cbuf) {
    int idx = blockIdx.x * 256 + threadIdx.x;
    if (idx < BATCH * KDIM) {
        int b = idx / KDIM, k = idx - b * KDIM;
        float v = (k < NINP) ? emb[tokens[b] * NINP + k] : 0.f;
        int c = k >> 5, q = (k >> 3) & 3, e = k & 7;
        A0[((size_t)(b >> 4) * NCHUNK + c) * 512 + (q * 16 + (b & 15)) * 8 + e] = f2b(v);
    }
    if (idx < BATCH * NHID) cbuf[idx] = 0.f;
}

// ---- one LSTM step: 256 blocks x 512 threads, 16 cols/block, depth-3 pipeline ----
__global__ __launch_bounds__(512, 2)
void k_step(int t, const ushort_t* __restrict__ Wp, const float* __restrict__ bias,
            const ushort_t* __restrict__ Ac, ushort_t* __restrict__ An,
            float* __restrict__ cbuf, float* __restrict__ out,
            const int* __restrict__ tokens, const int* __restrict__ seq_len,
            const float* __restrict__ emb) {
    const int tid  = threadIdx.x;
    const int wave = tid >> 6;          // 0..7
    const int lane = tid & 63;
    const int bx   = blockIdx.x;
    const int j0   = bx * 16;

    __shared__ float sbuf[BATCH][66];   // [batch][gt*16 + n], pad 66

    for (int i2 = tid; i2 < BATCH * 66; i2 += 512) (&sbuf[0][0])[i2] = 0.f;

    // K-chunk split: waves 0,1 -> 17 chunks, waves 2..7 -> 16 (sum 130)
    const int cstart = wave * 16 + (wave < 2 ? wave : 2);
    const int NC     = (wave < 2 ? 17 : 16);

    const ushort_t* pw0 = Wp + ((size_t)(0 * 256 + bx) * NCHUNK) * 512 + lane * 8;
    const ushort_t* pw1 = Wp + ((size_t)(1 * 256 + bx) * NCHUNK) * 512 + lane * 8;
    const ushort_t* pw2 = Wp + ((size_t)(2 * 256 + bx) * NCHUNK) * 512 + lane * 8;
    const ushort_t* pw3 = Wp + ((size_t)(3 * 256 + bx) * NCHUNK) * 512 + lane * 8;
    const ushort_t* pa0 = Ac + ((size_t)0 * NCHUNK) * 512 + lane * 8;
    const ushort_t* pa1 = Ac + ((size_t)1 * NCHUNK) * 512 + lane * 8;
    const ushort_t* pa2 = Ac + ((size_t)2 * NCHUNK) * 512 + lane * 8;
    const ushort_t* pa3 = Ac + ((size_t)3 * NCHUNK) * 512 + lane * 8;

    f32x4 acc[4][4];                    // [rt batch-tile][gt]
    #pragma unroll
    for (int rt = 0; rt < 4; ++rt)
        #pragma unroll
        for (int gt = 0; gt < 4; ++gt)
            acc[rt][gt] = (f32x4){0.f, 0.f, 0.f, 0.f};

    #define LOADF(WD, AD, cc) do {                                        \
        const size_t _o = (size_t)(cc) * 512;                             \
        WD[0] = *reinterpret_cast<const bf16x8*>(pw0 + _o);               \
        WD[1] = *reinterpret_cast<const bf16x8*>(pw1 + _o);               \
        WD[2] = *reinterpret_cast<const bf16x8*>(pw2 + _o);               \
        WD[3] = *reinterpret_cast<const bf16x8*>(pw3 + _o);               \
        AD[0] = *reinterpret_cast<const bf16x8*>(pa0 + _o);               \
        AD[1] = *reinterpret_cast<const bf16x8*>(pa1 + _o);               \
        AD[2] = *reinterpret_cast<const bf16x8*>(pa2 + _o);               \
        AD[3] = *reinterpret_cast<const bf16x8*>(pa3 + _o);               \
    } while (0)

    #define DOMFMA(WD, AD) do {                                           \
        _Pragma("unroll")                                                 \
        for (int _rt = 0; _rt < 4; ++_rt) {                               \
            _Pragma("unroll")                                             \
            for (int _gt = 0; _gt < 4; ++_gt)                             \
                acc[_rt][_gt] = __builtin_amdgcn_mfma_f32_16x16x32_bf16(  \
                    AD[_rt], WD[_gt], acc[_rt][_gt], 0, 0, 0);            \
        }                                                                 \
    } while (0)

    // depth-3 ring, statically named buffers (no rotation, no runtime indexing)
    bf16x8 wA[4], xA[4], wB[4], xB[4], wC[4], xC[4];
    LOADF(wA, xA, cstart);
    LOADF(wB, xB, cstart + 1);
    LOADF(wC, xC, cstart + 2);
    int i = 0;
    for (; i + 5 < NC; i += 3) {
        DOMFMA(wA, xA); LOADF(wA, xA, cstart + i + 3);
        DOMFMA(wB, xB); LOADF(wB, xB, cstart + i + 4);
        DOMFMA(wC, xC); LOADF(wC, xC, cstart + i + 5);
    }
    // remainder: NC - i in {3,4,5}
    DOMFMA(wA, xA); if (i + 3 < NC) LOADF(wA, xA, cstart + i + 3);
    DOMFMA(wB, xB); if (i + 4 < NC) LOADF(wB, xB, cstart + i + 4);
    DOMFMA(wC, xC);
    if (i + 3 < NC) DOMFMA(wA, xA);
    if (i + 4 < NC) DOMFMA(wB, xB);
    #undef LOADF
    #undef DOMFMA

    __syncthreads();                    // sbuf zeros visible
    {
        // C/D layout: col n = lane&15 (group row), row = (lane>>4)*4 + r (batch)
        const int n = lane & 15, q = lane >> 4;
        #pragma unroll
        for (int rt = 0; rt < 4; ++rt)
            #pragma unroll
            for (int gt = 0; gt < 4; ++gt)
                #pragma unroll
                for (int r = 0; r < 4; ++r)
                    atomicAdd(&sbuf[rt * 16 + q * 4 + r][gt * 16 + n], acc[rt][gt][r]);
    }
    __syncthreads();

    // cell update: thread (wave, lane) -> batch b=lane, cols jl = wave, wave+8
    {
        const int b  = lane;
        const int sl = seq_len[b];
        #pragma unroll
        for (int jj = 0; jj < 2; ++jj) {
            const int jl = wave + jj * 8;          // 0..15
            const int j  = j0 + jl;
            float ig = sbuf[b][ 0 + jl] + bias[           j];
            float fg = sbuf[b][16 + jl] + bias[    NHID + j];
            float gg = sbuf[b][32 + jl] + bias[2 * NHID + j];
            float og = sbuf[b][48 + jl] + bias[3 * NHID + j];
            int cidx = b * NHID + j;
            float cold = cbuf[cidx];
            float cn = sigf(fg) * cold + sigf(ig) * tanhf(gg);
            float hn = sigf(og) * tanhf(cn);
            cbuf[cidx] = cn;
            if (t == sl - 1) out[cidx] = cn;       // final feature only
            const int kk = NINP + j;               // h position in A' k-dim
            const int c = kk >> 5, q2 = (kk >> 3) & 3, e = kk & 7;
            An[((size_t)(b >> 4) * NCHUNK + c) * 512 + (q2 * 16 + (b & 15)) * 8 + e] = f2b(hn);
        }
        // next-step embedding, distributed: 16 values per block
        if (tid < 16 && (t + 1) < TSTEPS) {
            const int eb  = bx >> 2;               // batch row 0..63
            const int k   = (bx & 3) * 16 + tid;   // k index 0..63
            const int tok = tokens[(t + 1) * BATCH + eb];
            const float v = emb[tok * NINP + k];
            const int c2 = k >> 5, q3 = (k >> 3) & 3, e2 = k & 7;
            An[((size_t)(eb >> 4) * NCHUNK + c2) * 512 + (q3 * 16 + (eb & 15)) * 8 + e2] = f2b(v);
        }
    }
}

extern "C" void kernel_launch(void* const* d_in, const int* in_sizes, int n_in,
                              void* d_out, int out_size, void* d_ws, size_t ws_size,
                              hipStream_t stream) {
    const int*   tokens  = (const int*)d_in[0];
    const int*   seq_len = (const int*)d_in[1];
    const float* emb     = (const float*)d_in[2];
    const float* w_ih    = (const float*)d_in[3];
    const float* w_hh    = (const float*)d_in[4];
    const float* b_ih    = (const float*)d_in[5];
    const float* b_hh    = (const float*)d_in[6];
    float* out = (float*)d_out;

    char* ws = (char*)d_ws;
    const size_t W_BYTES    = (size_t)NGRP * NCHUNK * 512 * 2;  // 136,314,880
    const size_t BIAS_BYTES = (size_t)NGATE * 4;                // 65,536
    const size_t C_BYTES    = (size_t)BATCH * NHID * 4;         // 1,048,576
    const size_t A_BYTES    = (size_t)4 * NCHUNK * 512 * 2;     // 532,480

    ushort_t* Wp   = (ushort_t*)ws;
    float*    bias = (float*)(ws + W_BYTES);
    float*    cbuf = (float*)(ws + W_BYTES + BIAS_BYTES);
    ushort_t* A0   = (ushort_t*)(ws + W_BYTES + BIAS_BYTES + C_BYTES);
    ushort_t* A1   = (ushort_t*)(ws + W_BYTES + BIAS_BYTES + C_BYTES + A_BYTES);

    k_convert<<<NGRP, 256, 0, stream>>>(w_ih, w_hh, b_ih, b_hh, Wp, bias);

    int init_elems = BATCH * KDIM;
    k_init<<<(init_elems + 255) / 256, 256, 0, stream>>>(tokens, emb, A0, cbuf);

    for (int t = 0; t < TSTEPS; ++t) {
        ushort_t* Acur  = (t & 1) ? A1 : A0;
        ushort_t* Anext = (t & 1) ? A0 : A1;
        k_step<<<NBLK, 512, 0, stream>>>(t, Wp, bias, Acur, Anext, cbuf, out,
                                         tokens, seq_len, emb);
    }
}